// Round 1
// baseline (935.217 us; speedup 1.0000x reference)
//
#include <hip/hip_runtime.h>

#define C 128

// ---------------- degree ----------------
__global__ __launch_bounds__(256) void k_init_deg(float* __restrict__ deg, int n) {
    int i = blockIdx.x * 256 + threadIdx.x;
    if (i < n) deg[i] = 1.0f;  // self-loop weight
}

__global__ __launch_bounds__(256) void k_deg(const int* __restrict__ col,
                                             const float* __restrict__ ew,
                                             float* __restrict__ deg, int nE) {
    int e = blockIdx.x * 256 + threadIdx.x;
    if (e < nE) atomicAdd(&deg[col[e]], ew[e]);
}

__global__ __launch_bounds__(256) void k_dis(float* __restrict__ deg, int n) {
    int i = blockIdx.x * 256 + threadIdx.x;
    if (i < n) {
        float v = deg[i];
        deg[i] = v > 0.0f ? rsqrtf(v) : 0.0f;
    }
}

// ---------------- h = x @ W, fused self-loop write: out = h * dis^2 ----------------
// Block: 256 threads, 32 rows per block. W (64KB) + x rows (16KB) in LDS.
__global__ __launch_bounds__(256) void k_gemm(const float* __restrict__ x,
                                              const float* __restrict__ W,
                                              const float* __restrict__ dis,
                                              float* __restrict__ h,
                                              float* __restrict__ out, int n) {
    __shared__ float Ws[C * C];     // 64 KB
    __shared__ float xs[32 * C];    // 16 KB
    const int t = threadIdx.x;

    for (int i = t * 4; i < C * C; i += 256 * 4)
        *(float4*)&Ws[i] = *(const float4*)&W[i];

    const int row0 = blockIdx.x * 32;
    for (int i = t * 4; i < 32 * C; i += 256 * 4) {
        int r = row0 + (i >> 7);
        float4 v = make_float4(0.f, 0.f, 0.f, 0.f);
        if (r < n) v = *(const float4*)&x[(size_t)row0 * C + i];
        *(float4*)&xs[i] = v;
    }
    __syncthreads();

    const float4* Ws4 = (const float4*)Ws;
    const float4* xs4 = (const float4*)xs;
    const int cg = t & 31;   // channel group: channels cg*4 .. cg*4+3
    const int r0 = t >> 5;   // row offset 0..7

    for (int r = r0; r < 32; r += 8) {
        float4 a = make_float4(0.f, 0.f, 0.f, 0.f);
#pragma unroll
        for (int k4 = 0; k4 < 32; ++k4) {
            float4 xv = xs4[r * 32 + k4];
            float4 w0 = Ws4[(k4 * 4 + 0) * 32 + cg];
            float4 w1 = Ws4[(k4 * 4 + 1) * 32 + cg];
            float4 w2 = Ws4[(k4 * 4 + 2) * 32 + cg];
            float4 w3 = Ws4[(k4 * 4 + 3) * 32 + cg];
            a.x = fmaf(xv.x, w0.x, a.x); a.y = fmaf(xv.x, w0.y, a.y);
            a.z = fmaf(xv.x, w0.z, a.z); a.w = fmaf(xv.x, w0.w, a.w);
            a.x = fmaf(xv.y, w1.x, a.x); a.y = fmaf(xv.y, w1.y, a.y);
            a.z = fmaf(xv.y, w1.z, a.z); a.w = fmaf(xv.y, w1.w, a.w);
            a.x = fmaf(xv.z, w2.x, a.x); a.y = fmaf(xv.z, w2.y, a.y);
            a.z = fmaf(xv.z, w2.z, a.z); a.w = fmaf(xv.z, w2.w, a.w);
            a.x = fmaf(xv.w, w3.x, a.x); a.y = fmaf(xv.w, w3.y, a.y);
            a.z = fmaf(xv.w, w3.z, a.z); a.w = fmaf(xv.w, w3.w, a.w);
        }
        int row = row0 + r;
        if (row < n) {
            float d = dis[row];
            float d2 = d * d;
            ((float4*)h)[(size_t)row * 32 + cg] = a;
            float4 o = make_float4(a.x * d2, a.y * d2, a.z * d2, a.w * d2);
            ((float4*)out)[(size_t)row * 32 + cg] = o;
        }
    }
}

// ---------------- edge scatter: out[col] += h[row] * (dis[row]*w*dis[col]) ----------------
// 2 edges per 256-thread block; 128 consecutive channels per edge (coalesced).
__global__ __launch_bounds__(256) void k_scatter(const int* __restrict__ ei,
                                                 const float* __restrict__ ew,
                                                 const float* __restrict__ dis,
                                                 const float* __restrict__ h,
                                                 float* __restrict__ out, int nE) {
    int c = threadIdx.x & 127;
    int e = blockIdx.x * 2 + (threadIdx.x >> 7);
    if (e >= nE) return;
    int row = ei[e];
    int col = ei[nE + e];
    float norm = dis[row] * ew[e] * dis[col];
    float v = h[(size_t)row * C + c] * norm;
    atomicAdd(&out[(size_t)col * C + c], v);
}

// ---------------- BN stats: per-channel sum & sumsq ----------------
__global__ __launch_bounds__(256) void k_stats(const float* __restrict__ out,
                                               float* __restrict__ sums, int n) {
    int c = threadIdx.x & 127;
    int half = threadIdx.x >> 7;
    float s = 0.f, s2 = 0.f;
    for (int r = blockIdx.x * 2 + half; r < n; r += gridDim.x * 2) {
        float v = out[(size_t)r * C + c];
        s += v;
        s2 = fmaf(v, v, s2);
    }
    __shared__ float ls[512];
    ls[threadIdx.x] = s;
    ls[256 + threadIdx.x] = s2;
    __syncthreads();
    if (half == 0) {
        atomicAdd(&sums[c], ls[c] + ls[c + 128]);
        atomicAdd(&sums[C + c], ls[256 + c] + ls[256 + c + 128]);
    }
}

// ---------------- BN apply + ReLU (in place) ----------------
__global__ __launch_bounds__(256) void k_apply(float* __restrict__ out,
                                               const float* __restrict__ sums,
                                               const float* __restrict__ gamma,
                                               const float* __restrict__ beta,
                                               int n) {
    size_t idx = (size_t)blockIdx.x * 256 + threadIdx.x;  // float4 index
    size_t total = (size_t)n * 32;
    if (idx >= total) return;
    int cg = (int)(idx & 31);
    int c0 = cg * 4;
    float inv_n = 1.0f / (float)n;
    float4 v = ((const float4*)out)[idx];
    float4 r;
    {
        float mean = sums[c0 + 0] * inv_n;
        float var  = fmaxf(sums[C + c0 + 0] * inv_n - mean * mean, 0.f);
        float sc   = rsqrtf(var + 1e-5f) * gamma[c0 + 0];
        r.x = fmaxf(fmaf(v.x - mean, sc, beta[c0 + 0]), 0.f);
    }
    {
        float mean = sums[c0 + 1] * inv_n;
        float var  = fmaxf(sums[C + c0 + 1] * inv_n - mean * mean, 0.f);
        float sc   = rsqrtf(var + 1e-5f) * gamma[c0 + 1];
        r.y = fmaxf(fmaf(v.y - mean, sc, beta[c0 + 1]), 0.f);
    }
    {
        float mean = sums[c0 + 2] * inv_n;
        float var  = fmaxf(sums[C + c0 + 2] * inv_n - mean * mean, 0.f);
        float sc   = rsqrtf(var + 1e-5f) * gamma[c0 + 2];
        r.z = fmaxf(fmaf(v.z - mean, sc, beta[c0 + 2]), 0.f);
    }
    {
        float mean = sums[c0 + 3] * inv_n;
        float var  = fmaxf(sums[C + c0 + 3] * inv_n - mean * mean, 0.f);
        float sc   = rsqrtf(var + 1e-5f) * gamma[c0 + 3];
        r.w = fmaxf(fmaf(v.w - mean, sc, beta[c0 + 3]), 0.f);
    }
    ((float4*)out)[idx] = r;
}

extern "C" void kernel_launch(void* const* d_in, const int* in_sizes, int n_in,
                              void* d_out, int out_size, void* d_ws, size_t ws_size,
                              hipStream_t stream) {
    const float* x     = (const float*)d_in[0];
    const int*   ei    = (const int*)d_in[1];   // [2, E] flattened: row = ei[e], col = ei[E+e]
    const float* ew    = (const float*)d_in[2];
    const float* W     = (const float*)d_in[3];
    const float* gamma = (const float*)d_in[4];
    const float* beta  = (const float*)d_in[5];

    const int n  = in_sizes[0] / C;
    const int nE = in_sizes[2];

    float* out = (float*)d_out;
    char* ws = (char*)d_ws;
    float* h    = (float*)ws;                            // n*C floats (51.2 MB)
    float* deg  = (float*)(ws + (size_t)n * C * 4);      // n floats (becomes dis in place)
    float* sums = deg + n;                               // 256 floats: [sum(128), sumsq(128)]

    hipMemsetAsync(sums, 0, 256 * sizeof(float), stream);

    k_init_deg<<<(n + 255) / 256, 256, 0, stream>>>(deg, n);
    k_deg<<<(nE + 255) / 256, 256, 0, stream>>>(ei + nE, ew, deg, nE);
    k_dis<<<(n + 255) / 256, 256, 0, stream>>>(deg, n);
    k_gemm<<<(n + 31) / 32, 256, 0, stream>>>(x, W, deg, h, out, n);
    k_scatter<<<(nE + 1) / 2, 256, 0, stream>>>(ei, ew, deg, h, out, nE);
    k_stats<<<256, 256, 0, stream>>>(out, sums, n);
    k_apply<<<(int)(((size_t)n * 32 + 255) / 256), 256, 0, stream>>>(out, sums, gamma, beta, n);
}

// Round 2
// 912.413 us; speedup vs baseline: 1.0250x; 1.0250x over previous
//
#include <hip/hip_runtime.h>

#define C 128
typedef unsigned int uint;
typedef unsigned short ushort;

// ---------------- degree + histogram ----------------
__global__ __launch_bounds__(256) void k_init_deg(float* __restrict__ deg, int n) {
    int i = blockIdx.x * 256 + threadIdx.x;
    if (i < n) deg[i] = 1.0f;  // self-loop weight
}

__global__ __launch_bounds__(256) void k_deg_hist(const int* __restrict__ col,
                                                  const float* __restrict__ ew,
                                                  float* __restrict__ deg,
                                                  int* __restrict__ cnt, int nE) {
    int e = blockIdx.x * 256 + threadIdx.x;
    if (e < nE) {
        int c = col[e];
        atomicAdd(&deg[c], ew[e]);
        atomicAdd(&cnt[c], 1);
    }
}

__global__ __launch_bounds__(256) void k_dis(float* __restrict__ deg, int n) {
    int i = blockIdx.x * 256 + threadIdx.x;
    if (i < n) {
        float v = deg[i];
        deg[i] = v > 0.0f ? rsqrtf(v) : 0.0f;
    }
}

// ---------------- exclusive scan over cnt[n] -> offs[n+1] ----------------
__global__ __launch_bounds__(256) void k_scan1(const int* __restrict__ cnt,
                                               int* __restrict__ offs,
                                               int* __restrict__ bsum, int n) {
    __shared__ int s[256];
    int t = threadIdx.x;
    int i = blockIdx.x * 256 + t;
    int v = (i < n) ? cnt[i] : 0;
    s[t] = v;
    __syncthreads();
    for (int d = 1; d < 256; d <<= 1) {
        int a = (t >= d) ? s[t - d] : 0;
        __syncthreads();
        s[t] += a;
        __syncthreads();
    }
    if (i < n) offs[i] = s[t] - v;          // exclusive within block
    if (t == 255) bsum[blockIdx.x] = s[255]; // block total
}

__global__ __launch_bounds__(512) void k_scan2(int* __restrict__ bsum, int nb) {
    __shared__ int s[512];
    int t = threadIdx.x;
    int v = (t < nb) ? bsum[t] : 0;
    s[t] = v;
    __syncthreads();
    for (int d = 1; d < 512; d <<= 1) {
        int a = (t >= d) ? s[t - d] : 0;
        __syncthreads();
        s[t] += a;
        __syncthreads();
    }
    if (t < nb) bsum[t] = s[t] - v;          // exclusive
}

__global__ __launch_bounds__(256) void k_scan3(int* __restrict__ offs,
                                               const int* __restrict__ bsum,
                                               int n, int nE) {
    int i = blockIdx.x * 256 + threadIdx.x;
    if (i < n) offs[i] += bsum[i >> 8];
    if (i == 0) offs[n] = nE;
}

// ---------------- bin edges into CSR: ev[pos] = {row, norm} ----------------
__global__ __launch_bounds__(256) void k_build(const int* __restrict__ ei,
                                               const float* __restrict__ ew,
                                               const float* __restrict__ dis,
                                               const int* __restrict__ offs,
                                               int* __restrict__ cursor,
                                               int2* __restrict__ ev, int nE) {
    int e = blockIdx.x * 256 + threadIdx.x;
    if (e >= nE) return;
    int row = ei[e];
    int col = ei[nE + e];
    float norm = dis[row] * ew[e] * dis[col];
    int pos = offs[col] + atomicAdd(&cursor[col], 1);
    ev[pos] = make_int2(row, __float_as_int(norm));
}

// ---------------- x -> bf16 (RNE) ----------------
__global__ __launch_bounds__(256) void k_cvt(const uint4* __restrict__ x4,
                                             ushort4* __restrict__ xb4, long total4) {
    long i = (long)blockIdx.x * 256 + threadIdx.x;
    if (i >= total4) return;
    uint4 v = x4[i];
    ushort4 r;
    r.x = (ushort)((v.x + 0x7FFFu + ((v.x >> 16) & 1u)) >> 16);
    r.y = (ushort)((v.y + 0x7FFFu + ((v.y >> 16) & 1u)) >> 16);
    r.z = (ushort)((v.z + 0x7FFFu + ((v.z >> 16) & 1u)) >> 16);
    r.w = (ushort)((v.w + 0x7FFFu + ((v.w >> 16) & 1u)) >> 16);
    xb4[i] = r;
}

// ---------------- init agg with self-loop: out = dis^2 * x ----------------
__global__ __launch_bounds__(256) void k_initagg(const float4* __restrict__ x4,
                                                 const float* __restrict__ dis,
                                                 float4* __restrict__ out4, long total4) {
    long i = (long)blockIdx.x * 256 + threadIdx.x;
    if (i >= total4) return;
    float d = dis[i >> 5];
    float s = d * d;
    float4 v = x4[i];
    out4[i] = make_float4(v.x * s, v.y * s, v.z * s, v.w * s);
}

// ---------------- segment aggregation (no atomics): out[col] += sum norm*x[row] ----------------
__device__ __forceinline__ float bfld(const ushort* xb, int r, int c) {
    return __uint_as_float(((uint)xb[(size_t)r * C + c]) << 16);
}

__global__ __launch_bounds__(256) void k_segagg(const ushort* __restrict__ xb,
                                                const int2* __restrict__ ev,
                                                const int* __restrict__ offs,
                                                float* __restrict__ out, int n) {
    int c = threadIdx.x & 127;
    int col = blockIdx.x * 2 + (threadIdx.x >> 7);
    if (col >= n) return;
    int i = offs[col];
    const int end = offs[col + 1];
    size_t oidx = (size_t)col * C + c;
    float acc = out[oidx];
    for (; i + 4 <= end; i += 4) {
        int2 e0 = ev[i], e1 = ev[i + 1], e2 = ev[i + 2], e3 = ev[i + 3];
        float x0 = bfld(xb, e0.x, c);
        float x1 = bfld(xb, e1.x, c);
        float x2 = bfld(xb, e2.x, c);
        float x3 = bfld(xb, e3.x, c);
        acc = fmaf(__int_as_float(e0.y), x0, acc);
        acc = fmaf(__int_as_float(e1.y), x1, acc);
        acc = fmaf(__int_as_float(e2.y), x2, acc);
        acc = fmaf(__int_as_float(e3.y), x3, acc);
    }
    for (; i < end; ++i) {
        int2 e = ev[i];
        acc = fmaf(__int_as_float(e.y), bfld(xb, e.x, c), acc);
    }
    out[oidx] = acc;
}

// ---------------- in-place GEMM: io = io @ W  (register-blocked 4 rows/thread) ----------------
__global__ __launch_bounds__(256) void k_gemm(float* __restrict__ io,
                                              const float* __restrict__ W, int n) {
    __shared__ float Ws[C * C];   // 64 KB
    __shared__ float xs[32 * C];  // 16 KB
    const int t = threadIdx.x;

    for (int i = t * 4; i < C * C; i += 1024)
        *(float4*)&Ws[i] = *(const float4*)&W[i];

    const int row0 = blockIdx.x * 32;
    for (int i = t * 4; i < 32 * C; i += 1024) {
        int r = row0 + (i >> 7);
        float4 v = make_float4(0.f, 0.f, 0.f, 0.f);
        if (r < n) v = *(const float4*)&io[(size_t)row0 * C + i];
        *(float4*)&xs[i] = v;
    }
    __syncthreads();

    const float4* Ws4 = (const float4*)Ws;
    const float4* xs4 = (const float4*)xs;
    const int cg = t & 31;  // channel group c0 = cg*4
    const int r0 = t >> 5;  // row 0..7

    float4 a0 = make_float4(0.f, 0.f, 0.f, 0.f);
    float4 a1 = a0, a2 = a0, a3 = a0;

#define FMA16(A, XV)                                              \
    A.x = fmaf(XV.x, w0.x, A.x); A.y = fmaf(XV.x, w0.y, A.y);     \
    A.z = fmaf(XV.x, w0.z, A.z); A.w = fmaf(XV.x, w0.w, A.w);     \
    A.x = fmaf(XV.y, w1.x, A.x); A.y = fmaf(XV.y, w1.y, A.y);     \
    A.z = fmaf(XV.y, w1.z, A.z); A.w = fmaf(XV.y, w1.w, A.w);     \
    A.x = fmaf(XV.z, w2.x, A.x); A.y = fmaf(XV.z, w2.y, A.y);     \
    A.z = fmaf(XV.z, w2.z, A.z); A.w = fmaf(XV.z, w2.w, A.w);     \
    A.x = fmaf(XV.w, w3.x, A.x); A.y = fmaf(XV.w, w3.y, A.y);     \
    A.z = fmaf(XV.w, w3.z, A.z); A.w = fmaf(XV.w, w3.w, A.w);

#pragma unroll
    for (int k4 = 0; k4 < 32; ++k4) {
        float4 w0 = Ws4[(k4 * 4 + 0) * 32 + cg];
        float4 w1 = Ws4[(k4 * 4 + 1) * 32 + cg];
        float4 w2 = Ws4[(k4 * 4 + 2) * 32 + cg];
        float4 w3 = Ws4[(k4 * 4 + 3) * 32 + cg];
        float4 x0 = xs4[(r0 + 0)  * 32 + k4];
        float4 x1 = xs4[(r0 + 8)  * 32 + k4];
        float4 x2 = xs4[(r0 + 16) * 32 + k4];
        float4 x3 = xs4[(r0 + 24) * 32 + k4];
        FMA16(a0, x0)
        FMA16(a1, x1)
        FMA16(a2, x2)
        FMA16(a3, x3)
    }
#undef FMA16

    if (row0 + r0 + 24 < n) {
        ((float4*)io)[(size_t)(row0 + r0 + 0)  * 32 + cg] = a0;
        ((float4*)io)[(size_t)(row0 + r0 + 8)  * 32 + cg] = a1;
        ((float4*)io)[(size_t)(row0 + r0 + 16) * 32 + cg] = a2;
        ((float4*)io)[(size_t)(row0 + r0 + 24) * 32 + cg] = a3;
    } else {
        if (row0 + r0 + 0  < n) ((float4*)io)[(size_t)(row0 + r0 + 0)  * 32 + cg] = a0;
        if (row0 + r0 + 8  < n) ((float4*)io)[(size_t)(row0 + r0 + 8)  * 32 + cg] = a1;
        if (row0 + r0 + 16 < n) ((float4*)io)[(size_t)(row0 + r0 + 16) * 32 + cg] = a2;
        if (row0 + r0 + 24 < n) ((float4*)io)[(size_t)(row0 + r0 + 24) * 32 + cg] = a3;
    }
}

// ---------------- BN stats ----------------
__global__ __launch_bounds__(256) void k_stats(const float* __restrict__ out,
                                               float* __restrict__ sums, int n) {
    int c = threadIdx.x & 127;
    int half = threadIdx.x >> 7;
    float s = 0.f, s2 = 0.f;
    for (int r = blockIdx.x * 2 + half; r < n; r += gridDim.x * 2) {
        float v = out[(size_t)r * C + c];
        s += v;
        s2 = fmaf(v, v, s2);
    }
    __shared__ float ls[512];
    ls[threadIdx.x] = s;
    ls[256 + threadIdx.x] = s2;
    __syncthreads();
    if (half == 0) {
        atomicAdd(&sums[c], ls[c] + ls[c + 128]);
        atomicAdd(&sums[C + c], ls[256 + c] + ls[256 + c + 128]);
    }
}

// ---------------- BN apply + ReLU (in place) ----------------
__global__ __launch_bounds__(256) void k_apply(float* __restrict__ out,
                                               const float* __restrict__ sums,
                                               const float* __restrict__ gamma,
                                               const float* __restrict__ beta,
                                               int n) {
    size_t idx = (size_t)blockIdx.x * 256 + threadIdx.x;  // float4 index
    size_t total = (size_t)n * 32;
    if (idx >= total) return;
    int cg = (int)(idx & 31);
    int c0 = cg * 4;
    float inv_n = 1.0f / (float)n;
    float4 v = ((const float4*)out)[idx];
    float4 r;
#define BN1(OUT, VIN, J)                                                   \
    {                                                                      \
        float mean = sums[c0 + J] * inv_n;                                 \
        float var  = fmaxf(sums[C + c0 + J] * inv_n - mean * mean, 0.f);   \
        float sc   = rsqrtf(var + 1e-5f) * gamma[c0 + J];                  \
        OUT = fmaxf(fmaf(VIN - mean, sc, beta[c0 + J]), 0.f);              \
    }
    BN1(r.x, v.x, 0)
    BN1(r.y, v.y, 1)
    BN1(r.z, v.z, 2)
    BN1(r.w, v.w, 3)
#undef BN1
    ((float4*)out)[idx] = r;
}

extern "C" void kernel_launch(void* const* d_in, const int* in_sizes, int n_in,
                              void* d_out, int out_size, void* d_ws, size_t ws_size,
                              hipStream_t stream) {
    const float* x     = (const float*)d_in[0];
    const int*   ei    = (const int*)d_in[1];   // [2, E]: row = ei[e], col = ei[E+e]
    const float* ew    = (const float*)d_in[2];
    const float* W     = (const float*)d_in[3];
    const float* gamma = (const float*)d_in[4];
    const float* beta  = (const float*)d_in[5];

    const int n  = in_sizes[0] / C;
    const int nE = in_sizes[2];
    const int nb = (n + 255) / 256;

    float* out = (float*)d_out;
    char* ws = (char*)d_ws;

    int2*   ev     = (int2*)ws;                               // E * 8 B
    ushort* xb     = (ushort*)(ws + (size_t)nE * 8);          // n*C * 2 B
    char*   p      = ws + (size_t)nE * 8 + (size_t)n * C * 2;
    float*  deg    = (float*)p;            p += (size_t)n * 4;        // becomes dis
    int*    cnt    = (int*)p;              p += (size_t)n * 4;
    int*    offs   = (int*)p;              p += (size_t)(n + 1) * 4;
    int*    cursor = (int*)p;              p += (size_t)n * 4;
    int*    bsum   = (int*)p;              p += 512 * 4;
    float*  sums   = (float*)p;

    const long total4 = (long)n * 32;  // n*C/4

    hipMemsetAsync(cnt, 0, (size_t)n * 4, stream);
    hipMemsetAsync(cursor, 0, (size_t)n * 4, stream);
    hipMemsetAsync(sums, 0, 256 * 4, stream);

    k_cvt<<<(int)((total4 + 255) / 256), 256, 0, stream>>>((const uint4*)x, (ushort4*)xb, total4);
    k_init_deg<<<(n + 255) / 256, 256, 0, stream>>>(deg, n);
    k_deg_hist<<<(nE + 255) / 256, 256, 0, stream>>>(ei + nE, ew, deg, cnt, nE);
    k_dis<<<(n + 255) / 256, 256, 0, stream>>>(deg, n);
    k_scan1<<<nb, 256, 0, stream>>>(cnt, offs, bsum, n);
    k_scan2<<<1, 512, 0, stream>>>(bsum, nb);
    k_scan3<<<nb, 256, 0, stream>>>(offs, bsum, n, nE);
    k_build<<<(nE + 255) / 256, 256, 0, stream>>>(ei, ew, deg, offs, cursor, ev, nE);
    k_initagg<<<(int)((total4 + 255) / 256), 256, 0, stream>>>((const float4*)x, deg, (float4*)out, total4);
    k_segagg<<<(n + 1) / 2, 256, 0, stream>>>(xb, ev, offs, out, n);
    k_gemm<<<(n + 31) / 32, 256, 0, stream>>>(out, W, n);
    k_stats<<<256, 256, 0, stream>>>(out, sums, n);
    k_apply<<<(int)((total4 + 255) / 256), 256, 0, stream>>>(out, sums, gamma, beta, n);
}

// Round 3
// 469.918 us; speedup vs baseline: 1.9902x; 1.9416x over previous
//
#include <hip/hip_runtime.h>

#define C 128
typedef unsigned int uint;
typedef unsigned short ushort;

// ---------------- degree + histogram ----------------
__global__ __launch_bounds__(256) void k_init_deg(float* __restrict__ deg, int n) {
    int i = blockIdx.x * 256 + threadIdx.x;
    if (i < n) deg[i] = 1.0f;  // self-loop weight
}

__global__ __launch_bounds__(256) void k_deg_hist(const int* __restrict__ col,
                                                  const float* __restrict__ ew,
                                                  float* __restrict__ deg,
                                                  int* __restrict__ cnt, int nE) {
    int e = blockIdx.x * 256 + threadIdx.x;
    if (e < nE) {
        int c = col[e];
        atomicAdd(&deg[c], ew[e]);
        atomicAdd(&cnt[c], 1);
    }
}

__global__ __launch_bounds__(256) void k_dis(float* __restrict__ deg, int n) {
    int i = blockIdx.x * 256 + threadIdx.x;
    if (i < n) {
        float v = deg[i];
        deg[i] = v > 0.0f ? rsqrtf(v) : 0.0f;
    }
}

// ---------------- exclusive scan over cnt[n] -> offs[n+1] ----------------
__global__ __launch_bounds__(256) void k_scan1(const int* __restrict__ cnt,
                                               int* __restrict__ offs,
                                               int* __restrict__ bsum, int n) {
    __shared__ int s[256];
    int t = threadIdx.x;
    int i = blockIdx.x * 256 + t;
    int v = (i < n) ? cnt[i] : 0;
    s[t] = v;
    __syncthreads();
    for (int d = 1; d < 256; d <<= 1) {
        int a = (t >= d) ? s[t - d] : 0;
        __syncthreads();
        s[t] += a;
        __syncthreads();
    }
    if (i < n) offs[i] = s[t] - v;
    if (t == 255) bsum[blockIdx.x] = s[255];
}

__global__ __launch_bounds__(512) void k_scan2(int* __restrict__ bsum, int nb) {
    __shared__ int s[512];
    int t = threadIdx.x;
    int v = (t < nb) ? bsum[t] : 0;
    s[t] = v;
    __syncthreads();
    for (int d = 1; d < 512; d <<= 1) {
        int a = (t >= d) ? s[t - d] : 0;
        __syncthreads();
        s[t] += a;
        __syncthreads();
    }
    if (t < nb) bsum[t] = s[t] - v;
}

__global__ __launch_bounds__(256) void k_scan3(int* __restrict__ offs,
                                               const int* __restrict__ bsum,
                                               int n, int nE) {
    int i = blockIdx.x * 256 + threadIdx.x;
    if (i < n) offs[i] += bsum[i >> 8];
    if (i == 0) offs[n] = nE;
}

// ---------------- bin edges into CSR: ev[pos] = {row, norm} ----------------
__global__ __launch_bounds__(256) void k_build(const int* __restrict__ ei,
                                               const float* __restrict__ ew,
                                               const float* __restrict__ dis,
                                               const int* __restrict__ offs,
                                               int* __restrict__ cursor,
                                               int2* __restrict__ ev, int nE) {
    int e = blockIdx.x * 256 + threadIdx.x;
    if (e >= nE) return;
    int row = ei[e];
    int col = ei[nE + e];
    float norm = dis[row] * ew[e] * dis[col];
    int pos = offs[col] + atomicAdd(&cursor[col], 1);
    ev[pos] = make_int2(row, __float_as_int(norm));
}

// ---------------- x -> bf16 (RNE) ----------------
__global__ __launch_bounds__(256) void k_cvt(const uint4* __restrict__ x4,
                                             ushort4* __restrict__ xb4, long total4) {
    long i = (long)blockIdx.x * 256 + threadIdx.x;
    if (i >= total4) return;
    uint4 v = x4[i];
    ushort4 r;
    r.x = (ushort)((v.x + 0x7FFFu + ((v.x >> 16) & 1u)) >> 16);
    r.y = (ushort)((v.y + 0x7FFFu + ((v.y >> 16) & 1u)) >> 16);
    r.z = (ushort)((v.z + 0x7FFFu + ((v.z >> 16) & 1u)) >> 16);
    r.w = (ushort)((v.w + 0x7FFFu + ((v.w >> 16) & 1u)) >> 16);
    xb4[i] = r;
}

// ---------------- segment aggregation, no atomics, self-loop fused ----------------
// 16 lanes per col (uint4 = 8 bf16 channels per lane), 16 cols per 256-block.
__device__ __forceinline__ float blo(uint u) { return __uint_as_float(u << 16); }
__device__ __forceinline__ float bhi(uint u) { return __uint_as_float(u & 0xFFFF0000u); }

__global__ __launch_bounds__(256) void k_segagg(const ushort* __restrict__ xb,
                                                const float* __restrict__ x,
                                                const int2* __restrict__ ev,
                                                const int* __restrict__ offs,
                                                const float* __restrict__ dis,
                                                float* __restrict__ out, int n) {
    const int lane = threadIdx.x & 15;   // 0..15
    const int sub  = threadIdx.x >> 4;   // 0..15
    const int col  = blockIdx.x * 16 + sub;
    if (col >= n) return;

    // self-loop init: acc = dis^2 * x[col]
    float d = dis[col];
    float d2 = d * d;
    const float4* xr = (const float4*)(x + (size_t)col * C) + lane * 2;
    float4 s0 = xr[0], s1 = xr[1];
    float acc[8] = {d2 * s0.x, d2 * s0.y, d2 * s0.z, d2 * s0.w,
                    d2 * s1.x, d2 * s1.y, d2 * s1.z, d2 * s1.w};

    int i = offs[col];
    const int end = offs[col + 1];

#define EDGE(E, V)                                                        \
    {                                                                     \
        float nw = __int_as_float(E.y);                                   \
        acc[0] = fmaf(nw, blo(V.x), acc[0]);                              \
        acc[1] = fmaf(nw, bhi(V.x), acc[1]);                              \
        acc[2] = fmaf(nw, blo(V.y), acc[2]);                              \
        acc[3] = fmaf(nw, bhi(V.y), acc[3]);                              \
        acc[4] = fmaf(nw, blo(V.z), acc[4]);                              \
        acc[5] = fmaf(nw, bhi(V.z), acc[5]);                              \
        acc[6] = fmaf(nw, blo(V.w), acc[6]);                              \
        acc[7] = fmaf(nw, bhi(V.w), acc[7]);                              \
    }

    for (; i + 2 <= end; i += 2) {
        int2 e0 = ev[i], e1 = ev[i + 1];
        uint4 v0 = *(const uint4*)(xb + (size_t)e0.x * C + lane * 8);
        uint4 v1 = *(const uint4*)(xb + (size_t)e1.x * C + lane * 8);
        EDGE(e0, v0)
        EDGE(e1, v1)
    }
    if (i < end) {
        int2 e0 = ev[i];
        uint4 v0 = *(const uint4*)(xb + (size_t)e0.x * C + lane * 8);
        EDGE(e0, v0)
    }
#undef EDGE

    float4* orow = (float4*)(out + (size_t)col * C) + lane * 2;
    orow[0] = make_float4(acc[0], acc[1], acc[2], acc[3]);
    orow[1] = make_float4(acc[4], acc[5], acc[6], acc[7]);
}

// ---------------- in-place GEMM io = io @ W, BN stats fused ----------------
__global__ __launch_bounds__(256, 4) void k_gemm(float* __restrict__ io,
                                                 const float* __restrict__ W,
                                                 float* __restrict__ sums, int n) {
    __shared__ float Ws[C * C];   // 64 KB
    __shared__ float xs[32 * C];  // 16 KB (reused for stats reduction)
    const int t = threadIdx.x;

    for (int i = t * 4; i < C * C; i += 1024)
        *(float4*)&Ws[i] = *(const float4*)&W[i];

    const int row0 = blockIdx.x * 32;
    for (int i = t * 4; i < 32 * C; i += 1024) {
        int r = row0 + (i >> 7);
        float4 v = make_float4(0.f, 0.f, 0.f, 0.f);
        if (r < n) v = *(const float4*)&io[(size_t)row0 * C + i];
        *(float4*)&xs[i] = v;
    }
    __syncthreads();

    const float4* Ws4 = (const float4*)Ws;
    const float4* xs4 = (const float4*)xs;
    const int cg = t & 31;  // channel group c0 = cg*4
    const int r0 = t >> 5;  // row 0..7

    float4 a0 = make_float4(0.f, 0.f, 0.f, 0.f);
    float4 a1 = a0, a2 = a0, a3 = a0;

#define FMA16(A, XV)                                              \
    A.x = fmaf(XV.x, w0.x, A.x); A.y = fmaf(XV.x, w0.y, A.y);     \
    A.z = fmaf(XV.x, w0.z, A.z); A.w = fmaf(XV.x, w0.w, A.w);     \
    A.x = fmaf(XV.y, w1.x, A.x); A.y = fmaf(XV.y, w1.y, A.y);     \
    A.z = fmaf(XV.y, w1.z, A.z); A.w = fmaf(XV.y, w1.w, A.w);     \
    A.x = fmaf(XV.z, w2.x, A.x); A.y = fmaf(XV.z, w2.y, A.y);     \
    A.z = fmaf(XV.z, w2.z, A.z); A.w = fmaf(XV.z, w2.w, A.w);     \
    A.x = fmaf(XV.w, w3.x, A.x); A.y = fmaf(XV.w, w3.y, A.y);     \
    A.z = fmaf(XV.w, w3.z, A.z); A.w = fmaf(XV.w, w3.w, A.w);

#pragma unroll 4
    for (int k4 = 0; k4 < 32; ++k4) {
        float4 w0 = Ws4[(k4 * 4 + 0) * 32 + cg];
        float4 w1 = Ws4[(k4 * 4 + 1) * 32 + cg];
        float4 w2 = Ws4[(k4 * 4 + 2) * 32 + cg];
        float4 w3 = Ws4[(k4 * 4 + 3) * 32 + cg];
        float4 x0 = xs4[(r0 + 0)  * 32 + k4];
        float4 x1 = xs4[(r0 + 8)  * 32 + k4];
        float4 x2 = xs4[(r0 + 16) * 32 + k4];
        float4 x3 = xs4[(r0 + 24) * 32 + k4];
        FMA16(a0, x0)
        FMA16(a1, x1)
        FMA16(a2, x2)
        FMA16(a3, x3)
    }
#undef FMA16

    if (row0 + r0 + 24 < n) {
        ((float4*)io)[(size_t)(row0 + r0 + 0)  * 32 + cg] = a0;
        ((float4*)io)[(size_t)(row0 + r0 + 8)  * 32 + cg] = a1;
        ((float4*)io)[(size_t)(row0 + r0 + 16) * 32 + cg] = a2;
        ((float4*)io)[(size_t)(row0 + r0 + 24) * 32 + cg] = a3;
    } else {
        if (row0 + r0 + 0  < n) ((float4*)io)[(size_t)(row0 + r0 + 0)  * 32 + cg] = a0;
        if (row0 + r0 + 8  < n) ((float4*)io)[(size_t)(row0 + r0 + 8)  * 32 + cg] = a1;
        if (row0 + r0 + 16 < n) ((float4*)io)[(size_t)(row0 + r0 + 16) * 32 + cg] = a2;
        if (row0 + r0 + 24 < n) ((float4*)io)[(size_t)(row0 + r0 + 24) * 32 + cg] = a3;
    }

    // ---- fused BN stats: rows >= n contributed zeros (harmless) ----
    __syncthreads();             // all xs reads done; reuse xs as reduction buffer
    float* rsum = xs;            // [8][128]
    float* rsq  = xs + 1024;     // [8][128]
    const int ch = cg * 4;
#define ST(J, V0, V1, V2, V3)                                          \
    {                                                                  \
        float s = V0 + V1 + V2 + V3;                                   \
        float q = V0 * V0 + V1 * V1 + V2 * V2 + V3 * V3;               \
        rsum[r0 * 128 + ch + J] = s;                                   \
        rsq[r0 * 128 + ch + J] = q;                                    \
    }
    ST(0, a0.x, a1.x, a2.x, a3.x)
    ST(1, a0.y, a1.y, a2.y, a3.y)
    ST(2, a0.z, a1.z, a2.z, a3.z)
    ST(3, a0.w, a1.w, a2.w, a3.w)
#undef ST
    __syncthreads();
    if (t < 128) {
        float s = 0.f;
#pragma unroll
        for (int r = 0; r < 8; ++r) s += rsum[r * 128 + t];
        atomicAdd(&sums[t], s);
    } else {
        int c = t - 128;
        float q = 0.f;
#pragma unroll
        for (int r = 0; r < 8; ++r) q += rsq[r * 128 + c];
        atomicAdd(&sums[C + c], q);
    }
}

// ---------------- BN apply + ReLU (in place) ----------------
__global__ __launch_bounds__(256) void k_apply(float* __restrict__ out,
                                               const float* __restrict__ sums,
                                               const float* __restrict__ gamma,
                                               const float* __restrict__ beta,
                                               int n) {
    size_t idx = (size_t)blockIdx.x * 256 + threadIdx.x;  // float4 index
    size_t total = (size_t)n * 32;
    if (idx >= total) return;
    int cg = (int)(idx & 31);
    int c0 = cg * 4;
    float inv_n = 1.0f / (float)n;
    float4 v = ((const float4*)out)[idx];
    float4 r;
#define BN1(OUT, VIN, J)                                                   \
    {                                                                      \
        float mean = sums[c0 + J] * inv_n;                                 \
        float var  = fmaxf(sums[C + c0 + J] * inv_n - mean * mean, 0.f);   \
        float sc   = rsqrtf(var + 1e-5f) * gamma[c0 + J];                  \
        OUT = fmaxf(fmaf(VIN - mean, sc, beta[c0 + J]), 0.f);              \
    }
    BN1(r.x, v.x, 0)
    BN1(r.y, v.y, 1)
    BN1(r.z, v.z, 2)
    BN1(r.w, v.w, 3)
#undef BN1
    ((float4*)out)[idx] = r;
}

extern "C" void kernel_launch(void* const* d_in, const int* in_sizes, int n_in,
                              void* d_out, int out_size, void* d_ws, size_t ws_size,
                              hipStream_t stream) {
    const float* x     = (const float*)d_in[0];
    const int*   ei    = (const int*)d_in[1];   // [2, E]: row = ei[e], col = ei[E+e]
    const float* ew    = (const float*)d_in[2];
    const float* W     = (const float*)d_in[3];
    const float* gamma = (const float*)d_in[4];
    const float* beta  = (const float*)d_in[5];

    const int n  = in_sizes[0] / C;
    const int nE = in_sizes[2];
    const int nb = (n + 255) / 256;

    float* out = (float*)d_out;
    char* ws = (char*)d_ws;

    int2*   ev     = (int2*)ws;                               // E * 8 B
    ushort* xb     = (ushort*)(ws + (size_t)nE * 8);          // n*C * 2 B
    char*   p      = ws + (size_t)nE * 8 + (size_t)n * C * 2;
    float*  deg    = (float*)p;            p += (size_t)n * 4;        // becomes dis
    int*    cnt    = (int*)p;              p += (size_t)n * 4;
    int*    offs   = (int*)p;              p += (size_t)(n + 1) * 4;
    int*    cursor = (int*)p;              p += (size_t)n * 4;
    int*    bsum   = (int*)p;              p += 512 * 4;
    float*  sums   = (float*)p;

    const long total4 = (long)n * 32;  // n*C/4

    hipMemsetAsync(cnt, 0, (size_t)n * 4, stream);
    hipMemsetAsync(cursor, 0, (size_t)n * 4, stream);
    hipMemsetAsync(sums, 0, 256 * 4, stream);

    k_cvt<<<(int)((total4 + 255) / 256), 256, 0, stream>>>((const uint4*)x, (ushort4*)xb, total4);
    k_init_deg<<<(n + 255) / 256, 256, 0, stream>>>(deg, n);
    k_deg_hist<<<(nE + 255) / 256, 256, 0, stream>>>(ei + nE, ew, deg, cnt, nE);
    k_dis<<<(n + 255) / 256, 256, 0, stream>>>(deg, n);
    k_scan1<<<nb, 256, 0, stream>>>(cnt, offs, bsum, n);
    k_scan2<<<1, 512, 0, stream>>>(bsum, nb);
    k_scan3<<<nb, 256, 0, stream>>>(offs, bsum, n, nE);
    k_build<<<(nE + 255) / 256, 256, 0, stream>>>(ei, ew, deg, offs, cursor, ev, nE);
    k_segagg<<<(n + 15) / 16, 256, 0, stream>>>(xb, x, ev, offs, deg, out, n);
    k_gemm<<<(n + 31) / 32, 256, 0, stream>>>(out, W, sums, n);
    k_apply<<<(int)((total4 + 255) / 256), 256, 0, stream>>>(out, sums, gamma, beta, n);
}

// Round 4
// 340.769 us; speedup vs baseline: 2.7444x; 1.3790x over previous
//
#include <hip/hip_runtime.h>

#define C 128
typedef unsigned int uint;
typedef unsigned short ushort;
typedef unsigned long long u64;

// ---------------- pass 1: packed degree histogram + ticket ----------------
// packed[c]: hi32 = edge count, lo32 = sum(w) in 2^22 fixed point.
// atomicAdd's return value doubles as the CSR ticket (position within segment).
__global__ __launch_bounds__(256) void k_deg_hist(const int* __restrict__ col,
                                                  const float* __restrict__ ew,
                                                  u64* __restrict__ packed,
                                                  ushort* __restrict__ tkt, int nE) {
    int e = blockIdx.x * 256 + threadIdx.x;
    if (e >= nE) return;
    int c = col[e];
    u64 add = (1ull << 32) | (u64)(uint)__float2uint_rn(ew[e] * 4194304.0f);
    u64 old = atomicAdd(&packed[c], add);
    tkt[e] = (ushort)(old >> 32);
}

// ---------------- scan1: dis = rsqrt(1 + wsum) fused; exclusive scan of counts ----------------
__global__ __launch_bounds__(256) void k_scan1(const u64* __restrict__ packed,
                                               float* __restrict__ dis,
                                               int* __restrict__ offs,
                                               int* __restrict__ bsum, int n) {
    __shared__ int s[256];
    int t = threadIdx.x;
    int i = blockIdx.x * 256 + t;
    int v = 0;
    if (i < n) {
        u64 p = packed[i];
        v = (int)(p >> 32);
        float deg = 1.0f + (float)(p & 0xFFFFFFFFull) * 2.384185791015625e-7f;
        dis[i] = rsqrtf(deg);
    }
    s[t] = v;
    __syncthreads();
    for (int d = 1; d < 256; d <<= 1) {
        int a = (t >= d) ? s[t - d] : 0;
        __syncthreads();
        s[t] += a;
        __syncthreads();
    }
    if (i < n) offs[i] = s[t] - v;
    if (t == 255) bsum[blockIdx.x] = s[255];
}

__global__ __launch_bounds__(512) void k_scan2(int* __restrict__ bsum, int nb) {
    __shared__ int s[512];
    int t = threadIdx.x;
    int v = (t < nb) ? bsum[t] : 0;
    s[t] = v;
    __syncthreads();
    for (int d = 1; d < 512; d <<= 1) {
        int a = (t >= d) ? s[t - d] : 0;
        __syncthreads();
        s[t] += a;
        __syncthreads();
    }
    if (t < nb) bsum[t] = s[t] - v;
}

__global__ __launch_bounds__(256) void k_scan3(int* __restrict__ offs,
                                               const int* __restrict__ bsum,
                                               int n, int nE) {
    int i = blockIdx.x * 256 + threadIdx.x;
    if (i < n) offs[i] += bsum[i >> 8];
    if (i == 0) offs[n] = nE;
}

// ---------------- xb' = bf16(dis[r] * x[r]) ----------------
__global__ __launch_bounds__(256) void k_cvt(const float4* __restrict__ x4,
                                             const float* __restrict__ dis,
                                             ushort4* __restrict__ xb4, long total4) {
    long i = (long)blockIdx.x * 256 + threadIdx.x;
    if (i >= total4) return;
    float d = dis[i >> 5];
    float4 v = x4[i];
    ushort4 r;
#define RNE(OUT, F)                                                     \
    {                                                                   \
        uint u = __float_as_uint((F) * d);                              \
        OUT = (ushort)((u + 0x7FFFu + ((u >> 16) & 1u)) >> 16);         \
    }
    RNE(r.x, v.x) RNE(r.y, v.y) RNE(r.z, v.z) RNE(r.w, v.w)
#undef RNE
    xb4[i] = r;
}

// ---------------- bin edges into CSR (no atomics, no gathers) ----------------
__global__ __launch_bounds__(256) void k_build(const int* __restrict__ ei,
                                               const float* __restrict__ ew,
                                               const int* __restrict__ offs,
                                               const ushort* __restrict__ tkt,
                                               int2* __restrict__ ev, int nE) {
    int e = blockIdx.x * 256 + threadIdx.x;
    if (e >= nE) return;
    int row = ei[e];
    int c = ei[nE + e];
    int pos = offs[c] + tkt[e];
    ev[pos] = make_int2(row, __float_as_int(ew[e]));
}

// ---------------- segment aggregation ----------------
// out[col] = dis[col] * sum_e w_e * xb'[row_e]  +  dis[col]^2 * x[col]
// 16 lanes per col (uint4 = 8 bf16 channels per lane), 16 cols per 256-block.
__device__ __forceinline__ float blo(uint u) { return __uint_as_float(u << 16); }
__device__ __forceinline__ float bhi(uint u) { return __uint_as_float(u & 0xFFFF0000u); }

__global__ __launch_bounds__(256) void k_segagg(const ushort* __restrict__ xb,
                                                const float* __restrict__ x,
                                                const int2* __restrict__ ev,
                                                const int* __restrict__ offs,
                                                const float* __restrict__ dis,
                                                float* __restrict__ out, int n) {
    const int lane = threadIdx.x & 15;   // 0..15
    const int sub  = threadIdx.x >> 4;   // 0..15
    const int col  = blockIdx.x * 16 + sub;
    if (col >= n) return;

    float acc[8] = {0.f, 0.f, 0.f, 0.f, 0.f, 0.f, 0.f, 0.f};

    int i = offs[col];
    const int end = offs[col + 1];

#define EDGE(E, V)                                                        \
    {                                                                     \
        float nw = __int_as_float(E.y);                                   \
        acc[0] = fmaf(nw, blo(V.x), acc[0]);                              \
        acc[1] = fmaf(nw, bhi(V.x), acc[1]);                              \
        acc[2] = fmaf(nw, blo(V.y), acc[2]);                              \
        acc[3] = fmaf(nw, bhi(V.y), acc[3]);                              \
        acc[4] = fmaf(nw, blo(V.z), acc[4]);                              \
        acc[5] = fmaf(nw, bhi(V.z), acc[5]);                              \
        acc[6] = fmaf(nw, blo(V.w), acc[6]);                              \
        acc[7] = fmaf(nw, bhi(V.w), acc[7]);                              \
    }

    for (; i + 2 <= end; i += 2) {
        int2 e0 = ev[i], e1 = ev[i + 1];
        uint4 v0 = *(const uint4*)(xb + (size_t)e0.x * C + lane * 8);
        uint4 v1 = *(const uint4*)(xb + (size_t)e1.x * C + lane * 8);
        EDGE(e0, v0)
        EDGE(e1, v1)
    }
    if (i < end) {
        int2 e0 = ev[i];
        uint4 v0 = *(const uint4*)(xb + (size_t)e0.x * C + lane * 8);
        EDGE(e0, v0)
    }
#undef EDGE

    float d = dis[col];
    float d2 = d * d;
    const float4* xr = (const float4*)(x + (size_t)col * C) + lane * 2;
    float4 s0 = xr[0], s1 = xr[1];
    float4* orow = (float4*)(out + (size_t)col * C) + lane * 2;
    orow[0] = make_float4(fmaf(d, acc[0], d2 * s0.x), fmaf(d, acc[1], d2 * s0.y),
                          fmaf(d, acc[2], d2 * s0.z), fmaf(d, acc[3], d2 * s0.w));
    orow[1] = make_float4(fmaf(d, acc[4], d2 * s1.x), fmaf(d, acc[5], d2 * s1.y),
                          fmaf(d, acc[6], d2 * s1.z), fmaf(d, acc[7], d2 * s1.w));
}

// ---------------- in-place GEMM io = io @ W, BN stats fused ----------------
__global__ __launch_bounds__(256, 4) void k_gemm(float* __restrict__ io,
                                                 const float* __restrict__ W,
                                                 float* __restrict__ sums, int n) {
    __shared__ float Ws[C * C];   // 64 KB
    __shared__ float xs[32 * C];  // 16 KB (reused for stats reduction)
    const int t = threadIdx.x;

    for (int i = t * 4; i < C * C; i += 1024)
        *(float4*)&Ws[i] = *(const float4*)&W[i];

    const int row0 = blockIdx.x * 32;
    for (int i = t * 4; i < 32 * C; i += 1024) {
        int r = row0 + (i >> 7);
        float4 v = make_float4(0.f, 0.f, 0.f, 0.f);
        if (r < n) v = *(const float4*)&io[(size_t)row0 * C + i];
        *(float4*)&xs[i] = v;
    }
    __syncthreads();

    const float4* Ws4 = (const float4*)Ws;
    const float4* xs4 = (const float4*)xs;
    const int cg = t & 31;  // channel group c0 = cg*4
    const int r0 = t >> 5;  // row 0..7

    float4 a0 = make_float4(0.f, 0.f, 0.f, 0.f);
    float4 a1 = a0, a2 = a0, a3 = a0;

#define FMA16(A, XV)                                              \
    A.x = fmaf(XV.x, w0.x, A.x); A.y = fmaf(XV.x, w0.y, A.y);     \
    A.z = fmaf(XV.x, w0.z, A.z); A.w = fmaf(XV.x, w0.w, A.w);     \
    A.x = fmaf(XV.y, w1.x, A.x); A.y = fmaf(XV.y, w1.y, A.y);     \
    A.z = fmaf(XV.y, w1.z, A.z); A.w = fmaf(XV.y, w1.w, A.w);     \
    A.x = fmaf(XV.z, w2.x, A.x); A.y = fmaf(XV.z, w2.y, A.y);     \
    A.z = fmaf(XV.z, w2.z, A.z); A.w = fmaf(XV.z, w2.w, A.w);     \
    A.x = fmaf(XV.w, w3.x, A.x); A.y = fmaf(XV.w, w3.y, A.y);     \
    A.z = fmaf(XV.w, w3.z, A.z); A.w = fmaf(XV.w, w3.w, A.w);

#pragma unroll 4
    for (int k4 = 0; k4 < 32; ++k4) {
        float4 w0 = Ws4[(k4 * 4 + 0) * 32 + cg];
        float4 w1 = Ws4[(k4 * 4 + 1) * 32 + cg];
        float4 w2 = Ws4[(k4 * 4 + 2) * 32 + cg];
        float4 w3 = Ws4[(k4 * 4 + 3) * 32 + cg];
        float4 x0 = xs4[(r0 + 0)  * 32 + k4];
        float4 x1 = xs4[(r0 + 8)  * 32 + k4];
        float4 x2 = xs4[(r0 + 16) * 32 + k4];
        float4 x3 = xs4[(r0 + 24) * 32 + k4];
        FMA16(a0, x0)
        FMA16(a1, x1)
        FMA16(a2, x2)
        FMA16(a3, x3)
    }
#undef FMA16

    if (row0 + r0 + 24 < n) {
        ((float4*)io)[(size_t)(row0 + r0 + 0)  * 32 + cg] = a0;
        ((float4*)io)[(size_t)(row0 + r0 + 8)  * 32 + cg] = a1;
        ((float4*)io)[(size_t)(row0 + r0 + 16) * 32 + cg] = a2;
        ((float4*)io)[(size_t)(row0 + r0 + 24) * 32 + cg] = a3;
    } else {
        if (row0 + r0 + 0  < n) ((float4*)io)[(size_t)(row0 + r0 + 0)  * 32 + cg] = a0;
        if (row0 + r0 + 8  < n) ((float4*)io)[(size_t)(row0 + r0 + 8)  * 32 + cg] = a1;
        if (row0 + r0 + 16 < n) ((float4*)io)[(size_t)(row0 + r0 + 16) * 32 + cg] = a2;
        if (row0 + r0 + 24 < n) ((float4*)io)[(size_t)(row0 + r0 + 24) * 32 + cg] = a3;
    }

    // ---- fused BN stats: rows >= n contributed zeros (harmless) ----
    __syncthreads();
    float* rsum = xs;            // [8][128]
    float* rsq  = xs + 1024;     // [8][128]
    const int ch = cg * 4;
#define ST(J, V0, V1, V2, V3)                                          \
    {                                                                  \
        float s = V0 + V1 + V2 + V3;                                   \
        float q = V0 * V0 + V1 * V1 + V2 * V2 + V3 * V3;               \
        rsum[r0 * 128 + ch + J] = s;                                   \
        rsq[r0 * 128 + ch + J] = q;                                    \
    }
    ST(0, a0.x, a1.x, a2.x, a3.x)
    ST(1, a0.y, a1.y, a2.y, a3.y)
    ST(2, a0.z, a1.z, a2.z, a3.z)
    ST(3, a0.w, a1.w, a2.w, a3.w)
#undef ST
    __syncthreads();
    if (t < 128) {
        float s = 0.f;
#pragma unroll
        for (int r = 0; r < 8; ++r) s += rsum[r * 128 + t];
        atomicAdd(&sums[t], s);
    } else {
        int c = t - 128;
        float q = 0.f;
#pragma unroll
        for (int r = 0; r < 8; ++r) q += rsq[r * 128 + c];
        atomicAdd(&sums[C + c], q);
    }
}

// ---------------- BN apply + ReLU (in place) ----------------
__global__ __launch_bounds__(256) void k_apply(float* __restrict__ out,
                                               const float* __restrict__ sums,
                                               const float* __restrict__ gamma,
                                               const float* __restrict__ beta,
                                               int n) {
    size_t idx = (size_t)blockIdx.x * 256 + threadIdx.x;
    size_t total = (size_t)n * 32;
    if (idx >= total) return;
    int cg = (int)(idx & 31);
    int c0 = cg * 4;
    float inv_n = 1.0f / (float)n;
    float4 v = ((const float4*)out)[idx];
    float4 r;
#define BN1(OUT, VIN, J)                                                   \
    {                                                                      \
        float mean = sums[c0 + J] * inv_n;                                 \
        float var  = fmaxf(sums[C + c0 + J] * inv_n - mean * mean, 0.f);   \
        float sc   = rsqrtf(var + 1e-5f) * gamma[c0 + J];                  \
        OUT = fmaxf(fmaf(VIN - mean, sc, beta[c0 + J]), 0.f);              \
    }
    BN1(r.x, v.x, 0)
    BN1(r.y, v.y, 1)
    BN1(r.z, v.z, 2)
    BN1(r.w, v.w, 3)
#undef BN1
    ((float4*)out)[idx] = r;
}

extern "C" void kernel_launch(void* const* d_in, const int* in_sizes, int n_in,
                              void* d_out, int out_size, void* d_ws, size_t ws_size,
                              hipStream_t stream) {
    const float* x     = (const float*)d_in[0];
    const int*   ei    = (const int*)d_in[1];   // [2, E]: row = ei[e], col = ei[E+e]
    const float* ew    = (const float*)d_in[2];
    const float* W     = (const float*)d_in[3];
    const float* gamma = (const float*)d_in[4];
    const float* beta  = (const float*)d_in[5];

    const int n  = in_sizes[0] / C;
    const int nE = in_sizes[2];
    const int nb = (n + 255) / 256;

    float* out = (float*)d_out;
    char* ws = (char*)d_ws;

    int2*   ev     = (int2*)ws;                               // E*8 B
    ushort* xb     = (ushort*)(ws + (size_t)nE * 8);          // n*C*2 B
    char*   p      = ws + (size_t)nE * 8 + (size_t)n * C * 2;
    u64*    packed = (u64*)p;              p += (size_t)n * 8;
    float*  dis    = (float*)p;            p += (size_t)n * 4;
    int*    offs   = (int*)p;              p += (size_t)(n + 1) * 4;
    ushort* tkt    = (ushort*)p;           p += (size_t)nE * 2;
    int*    bsum   = (int*)p;              p += 512 * 4;
    float*  sums   = (float*)p;

    const long total4 = (long)n * 32;  // n*C/4

    hipMemsetAsync(packed, 0, (size_t)n * 8, stream);
    hipMemsetAsync(sums, 0, 256 * 4, stream);

    k_deg_hist<<<(nE + 255) / 256, 256, 0, stream>>>(ei + nE, ew, packed, tkt, nE);
    k_scan1<<<nb, 256, 0, stream>>>(packed, dis, offs, bsum, n);
    k_scan2<<<1, 512, 0, stream>>>(bsum, nb);
    k_scan3<<<nb, 256, 0, stream>>>(offs, bsum, n, nE);
    k_cvt<<<(int)((total4 + 255) / 256), 256, 0, stream>>>((const float4*)x, dis, (ushort4*)xb, total4);
    k_build<<<(nE + 255) / 256, 256, 0, stream>>>(ei, ew, offs, tkt, ev, nE);
    k_segagg<<<(n + 15) / 16, 256, 0, stream>>>(xb, x, ev, offs, dis, out, n);
    k_gemm<<<(n + 31) / 32, 256, 0, stream>>>(out, W, sums, n);
    k_apply<<<(int)((total4 + 255) / 256), 256, 0, stream>>>(out, sums, gamma, beta, n);
}

// Round 5
// 303.483 us; speedup vs baseline: 3.0816x; 1.1229x over previous
//
#include <hip/hip_runtime.h>

#define C 128
typedef unsigned int uint;
typedef unsigned short ushort;
typedef unsigned long long u64;
typedef __attribute__((ext_vector_type(4))) float f32x4;
typedef __attribute__((ext_vector_type(8))) short bf16x8;

// ---------------- pass 1: packed degree histogram + ticket ----------------
// packed[c]: hi32 = edge count, lo32 = sum(w) in 2^22 fixed point.
// atomicAdd's return value doubles as the CSR ticket (position within segment).
__global__ __launch_bounds__(256) void k_deg_hist(const int* __restrict__ col,
                                                  const float* __restrict__ ew,
                                                  u64* __restrict__ packed,
                                                  ushort* __restrict__ tkt, int nE) {
    int e = blockIdx.x * 256 + threadIdx.x;
    if (e >= nE) return;
    int c = col[e];
    u64 add = (1ull << 32) | (u64)(uint)__float2uint_rn(ew[e] * 4194304.0f);
    u64 old = atomicAdd(&packed[c], add);
    tkt[e] = (ushort)(old >> 32);
}

// ---------------- scan1: dis = rsqrt(1 + wsum) fused; exclusive scan of counts ----------------
__global__ __launch_bounds__(256) void k_scan1(const u64* __restrict__ packed,
                                               float* __restrict__ dis,
                                               int* __restrict__ offs,
                                               int* __restrict__ bsum, int n) {
    __shared__ int s[256];
    int t = threadIdx.x;
    int i = blockIdx.x * 256 + t;
    int v = 0;
    if (i < n) {
        u64 p = packed[i];
        v = (int)(p >> 32);
        float deg = 1.0f + (float)(p & 0xFFFFFFFFull) * 2.384185791015625e-7f;
        dis[i] = rsqrtf(deg);
    }
    s[t] = v;
    __syncthreads();
    for (int d = 1; d < 256; d <<= 1) {
        int a = (t >= d) ? s[t - d] : 0;
        __syncthreads();
        s[t] += a;
        __syncthreads();
    }
    if (i < n) offs[i] = s[t] - v;
    if (t == 255) bsum[blockIdx.x] = s[255];
}

__global__ __launch_bounds__(512) void k_scan2(int* __restrict__ bsum, int nb) {
    __shared__ int s[512];
    int t = threadIdx.x;
    int v = (t < nb) ? bsum[t] : 0;
    s[t] = v;
    __syncthreads();
    for (int d = 1; d < 512; d <<= 1) {
        int a = (t >= d) ? s[t - d] : 0;
        __syncthreads();
        s[t] += a;
        __syncthreads();
    }
    if (t < nb) bsum[t] = s[t] - v;
}

__global__ __launch_bounds__(256) void k_scan3(int* __restrict__ offs,
                                               const int* __restrict__ bsum,
                                               int n, int nE) {
    int i = blockIdx.x * 256 + threadIdx.x;
    if (i < n) offs[i] += bsum[i >> 8];
    if (i == 0) offs[n] = nE;
}

// ---------------- xb' = bf16(dis[r] * x[r]) ----------------
__global__ __launch_bounds__(256) void k_cvt(const float4* __restrict__ x4,
                                             const float* __restrict__ dis,
                                             ushort4* __restrict__ xb4, long total4) {
    long i = (long)blockIdx.x * 256 + threadIdx.x;
    if (i >= total4) return;
    float d = dis[i >> 5];
    float4 v = x4[i];
    ushort4 r;
#define RNE(OUT, F)                                                     \
    {                                                                   \
        uint u = __float_as_uint((F) * d);                              \
        OUT = (ushort)((u + 0x7FFFu + ((u >> 16) & 1u)) >> 16);         \
    }
    RNE(r.x, v.x) RNE(r.y, v.y) RNE(r.z, v.z) RNE(r.w, v.w)
#undef RNE
    xb4[i] = r;
}

// ---------------- WbT[o][k] = bf16(W[k][o]) ----------------
__global__ __launch_bounds__(256) void k_wcvt(const float* __restrict__ W,
                                              ushort* __restrict__ WbT) {
    int idx = blockIdx.x * 256 + threadIdx.x;   // 16384 total
    int k = idx >> 7, o = idx & 127;
    uint u = __float_as_uint(W[idx]);
    WbT[o * 128 + k] = (ushort)((u + 0x7FFFu + ((u >> 16) & 1u)) >> 16);
}

// ---------------- bin edges into CSR (no atomics, no gathers) ----------------
__global__ __launch_bounds__(256) void k_build(const int* __restrict__ ei,
                                               const float* __restrict__ ew,
                                               const int* __restrict__ offs,
                                               const ushort* __restrict__ tkt,
                                               int2* __restrict__ ev, int nE) {
    int e = blockIdx.x * 256 + threadIdx.x;
    if (e >= nE) return;
    int row = ei[e];
    int c = ei[nE + e];
    int pos = offs[c] + tkt[e];
    ev[pos] = make_int2(row, __float_as_int(ew[e]));
}

// ---------------- segment aggregation ----------------
// out[col] = dis[col] * ( xb'[col] + sum_e w_e * xb'[row_e] )   (self-loop = weight-1 edge)
__device__ __forceinline__ float blo(uint u) { return __uint_as_float(u << 16); }
__device__ __forceinline__ float bhi(uint u) { return __uint_as_float(u & 0xFFFF0000u); }

__global__ __launch_bounds__(256) void k_segagg(const ushort* __restrict__ xb,
                                                const int2* __restrict__ ev,
                                                const int* __restrict__ offs,
                                                const float* __restrict__ dis,
                                                float* __restrict__ out, int n) {
    const int lane = threadIdx.x & 15;   // 0..15
    const int sub  = threadIdx.x >> 4;   // 0..15
    const int col  = blockIdx.x * 16 + sub;
    if (col >= n) return;

    uint4 sv = *(const uint4*)(xb + (size_t)col * C + lane * 8);
    float acc[8] = {blo(sv.x), bhi(sv.x), blo(sv.y), bhi(sv.y),
                    blo(sv.z), bhi(sv.z), blo(sv.w), bhi(sv.w)};

    int i = offs[col];
    const int end = offs[col + 1];

#define EDGE(E, V)                                                        \
    {                                                                     \
        float nw = __int_as_float(E.y);                                   \
        acc[0] = fmaf(nw, blo(V.x), acc[0]);                              \
        acc[1] = fmaf(nw, bhi(V.x), acc[1]);                              \
        acc[2] = fmaf(nw, blo(V.y), acc[2]);                              \
        acc[3] = fmaf(nw, bhi(V.y), acc[3]);                              \
        acc[4] = fmaf(nw, blo(V.z), acc[4]);                              \
        acc[5] = fmaf(nw, bhi(V.z), acc[5]);                              \
        acc[6] = fmaf(nw, blo(V.w), acc[6]);                              \
        acc[7] = fmaf(nw, bhi(V.w), acc[7]);                              \
    }

    for (; i + 2 <= end; i += 2) {
        int2 e0 = ev[i], e1 = ev[i + 1];
        uint4 v0 = *(const uint4*)(xb + (size_t)e0.x * C + lane * 8);
        uint4 v1 = *(const uint4*)(xb + (size_t)e1.x * C + lane * 8);
        EDGE(e0, v0)
        EDGE(e1, v1)
    }
    if (i < end) {
        int2 e0 = ev[i];
        uint4 v0 = *(const uint4*)(xb + (size_t)e0.x * C + lane * 8);
        EDGE(e0, v0)
    }
#undef EDGE

    float d = dis[col];
    float4* orow = (float4*)(out + (size_t)col * C) + lane * 2;
    orow[0] = make_float4(d * acc[0], d * acc[1], d * acc[2], d * acc[3]);
    orow[1] = make_float4(d * acc[4], d * acc[5], d * acc[6], d * acc[7]);
}

// ---------------- MFMA GEMM: io = io @ W (in place), BN stats fused ----------------
// 4 waves/block, 16 rows/wave. A: f32 rows converted to bf16 in-register.
// B: WbT [col][k] bf16, 16B-contiguous per-lane frags.
__global__ __launch_bounds__(256, 4) void k_gemm(float* __restrict__ io,
                                                 const ushort* __restrict__ WbT,
                                                 float* __restrict__ sums, int n) {
    __shared__ float ls[256];
    const int t = threadIdx.x;
    ls[t] = 0.f;
    __syncthreads();

    const int lane = t & 63;
    const int wv = t >> 6;          // wave 0..3
    const int lr = lane & 15;       // row (A) / col (B,D) within tile
    const int lk = lane >> 4;       // k-chunk 0..3 (and D row-group)
    const long rowA = (long)blockIdx.x * 64 + wv * 16 + lr;
    const bool inr = rowA < (long)n;

    // ---- A fragments: 8 consecutive f32 -> bf16x8 (round-half-up) ----
    bf16x8 a[4];
#pragma unroll
    for (int kk = 0; kk < 4; ++kk) {
        uint4 q0 = make_uint4(0, 0, 0, 0), q1 = q0;
        if (inr) {
            const uint4* p = (const uint4*)(io + (size_t)rowA * C + kk * 32 + lk * 8);
            q0 = p[0];
            q1 = p[1];
        }
        union { uint u[4]; bf16x8 v; } cv;
        cv.u[0] = __builtin_amdgcn_perm(q0.y + 0x8000u, q0.x + 0x8000u, 0x07060302u);
        cv.u[1] = __builtin_amdgcn_perm(q0.w + 0x8000u, q0.z + 0x8000u, 0x07060302u);
        cv.u[2] = __builtin_amdgcn_perm(q1.y + 0x8000u, q1.x + 0x8000u, 0x07060302u);
        cv.u[3] = __builtin_amdgcn_perm(q1.w + 0x8000u, q1.z + 0x8000u, 0x07060302u);
        a[kk] = cv.v;
    }

    // ---- MFMA over 8 col-tiles ----
    f32x4 acc[8];
#pragma unroll
    for (int ct = 0; ct < 8; ++ct) acc[ct] = (f32x4){0.f, 0.f, 0.f, 0.f};

    const ushort* wb = WbT + lr * 128 + lk * 8;
#pragma unroll
    for (int ct = 0; ct < 8; ++ct) {
        bf16x8 b0 = *(const bf16x8*)(wb + ct * 2048);
        bf16x8 b1 = *(const bf16x8*)(wb + ct * 2048 + 32);
        bf16x8 b2 = *(const bf16x8*)(wb + ct * 2048 + 64);
        bf16x8 b3 = *(const bf16x8*)(wb + ct * 2048 + 96);
        acc[ct] = __builtin_amdgcn_mfma_f32_16x16x32_bf16(a[0], b0, acc[ct], 0, 0, 0);
        acc[ct] = __builtin_amdgcn_mfma_f32_16x16x32_bf16(a[1], b1, acc[ct], 0, 0, 0);
        acc[ct] = __builtin_amdgcn_mfma_f32_16x16x32_bf16(a[2], b2, acc[ct], 0, 0, 0);
        acc[ct] = __builtin_amdgcn_mfma_f32_16x16x32_bf16(a[3], b3, acc[ct], 0, 0, 0);
    }

    // ---- store D + BN partial stats (rows >= n hold zeros, contribute nothing) ----
    const long rowD0 = (long)blockIdx.x * 64 + wv * 16 + lk * 4;
#pragma unroll
    for (int ct = 0; ct < 8; ++ct) {
        const int colg = ct * 16 + lr;
        float s = 0.f, q = 0.f;
#pragma unroll
        for (int rg = 0; rg < 4; ++rg) {
            float v = acc[ct][rg];
            long r = rowD0 + rg;
            if (r < n) io[r * C + colg] = v;
            s += v;
            q = fmaf(v, v, q);
        }
        atomicAdd(&ls[colg], s);
        atomicAdd(&ls[128 + colg], q);
    }
    __syncthreads();
    atomicAdd(&sums[t], ls[t]);   // sums[0..127]=sum, sums[128..255]=sumsq
}

// ---------------- BN apply + ReLU (in place) ----------------
__global__ __launch_bounds__(256) void k_apply(float* __restrict__ out,
                                               const float* __restrict__ sums,
                                               const float* __restrict__ gamma,
                                               const float* __restrict__ beta,
                                               int n) {
    size_t idx = (size_t)blockIdx.x * 256 + threadIdx.x;
    size_t total = (size_t)n * 32;
    if (idx >= total) return;
    int cg = (int)(idx & 31);
    int c0 = cg * 4;
    float inv_n = 1.0f / (float)n;
    float4 v = ((const float4*)out)[idx];
    float4 r;
#define BN1(OUT, VIN, J)                                                   \
    {                                                                      \
        float mean = sums[c0 + J] * inv_n;                                 \
        float var  = fmaxf(sums[C + c0 + J] * inv_n - mean * mean, 0.f);   \
        float sc   = rsqrtf(var + 1e-5f) * gamma[c0 + J];                  \
        OUT = fmaxf(fmaf(VIN - mean, sc, beta[c0 + J]), 0.f);              \
    }
    BN1(r.x, v.x, 0)
    BN1(r.y, v.y, 1)
    BN1(r.z, v.z, 2)
    BN1(r.w, v.w, 3)
#undef BN1
    ((float4*)out)[idx] = r;
}

extern "C" void kernel_launch(void* const* d_in, const int* in_sizes, int n_in,
                              void* d_out, int out_size, void* d_ws, size_t ws_size,
                              hipStream_t stream) {
    const float* x     = (const float*)d_in[0];
    const int*   ei    = (const int*)d_in[1];   // [2, E]: row = ei[e], col = ei[E+e]
    const float* ew    = (const float*)d_in[2];
    const float* W     = (const float*)d_in[3];
    const float* gamma = (const float*)d_in[4];
    const float* beta  = (const float*)d_in[5];

    const int n  = in_sizes[0] / C;
    const int nE = in_sizes[2];
    const int nb = (n + 255) / 256;

    float* out = (float*)d_out;
    char* ws = (char*)d_ws;

    int2*   ev     = (int2*)ws;                               // E*8 B
    ushort* xb     = (ushort*)(ws + (size_t)nE * 8);          // n*C*2 B
    char*   p      = ws + (size_t)nE * 8 + (size_t)n * C * 2;
    u64*    packed = (u64*)p;              p += (size_t)n * 8;
    ushort* WbT    = (ushort*)p;           p += 128 * 128 * 2;
    float*  dis    = (float*)p;            p += (size_t)n * 4;
    int*    offs   = (int*)p;              p += (size_t)(n + 1) * 4;
    ushort* tkt    = (ushort*)p;           p += (size_t)nE * 2;
    int*    bsum   = (int*)p;              p += 512 * 4;
    float*  sums   = (float*)p;

    const long total4 = (long)n * 32;  // n*C/4

    hipMemsetAsync(packed, 0, (size_t)n * 8, stream);
    hipMemsetAsync(sums, 0, 256 * 4, stream);

    k_deg_hist<<<(nE + 255) / 256, 256, 0, stream>>>(ei + nE, ew, packed, tkt, nE);
    k_wcvt<<<64, 256, 0, stream>>>(W, WbT);
    k_scan1<<<nb, 256, 0, stream>>>(packed, dis, offs, bsum, n);
    k_scan2<<<1, 512, 0, stream>>>(bsum, nb);
    k_scan3<<<nb, 256, 0, stream>>>(offs, bsum, n, nE);
    k_cvt<<<(int)((total4 + 255) / 256), 256, 0, stream>>>((const float4*)x, dis, (ushort4*)xb, total4);
    k_build<<<(nE + 255) / 256, 256, 0, stream>>>(ei, ew, offs, tkt, ev, nE);
    k_segagg<<<(n + 15) / 16, 256, 0, stream>>>(xb, ev, offs, dis, out, n);
    k_gemm<<<(n + 63) / 64, 256, 0, stream>>>(out, WbT, sums, n);
    k_apply<<<(int)((total4 + 255) / 256), 256, 0, stream>>>(out, sums, gamma, beta, n);
}

// Round 6
// 272.779 us; speedup vs baseline: 3.4285x; 1.1126x over previous
//
#include <hip/hip_runtime.h>

#define C 128
typedef unsigned int uint;
typedef unsigned short ushort;
typedef unsigned long long u64;
typedef __attribute__((ext_vector_type(4))) float f32x4;
typedef __attribute__((ext_vector_type(8))) short bf16x8;

// ---------------- pass 1: packed degree histogram + ticket ----------------
// packed[c]: hi32 = edge count, lo32 = sum(w) in 2^22 fixed point.
// atomicAdd's return value doubles as the CSR ticket (position within segment).
__global__ __launch_bounds__(256) void k_deg_hist(const int* __restrict__ col,
                                                  const float* __restrict__ ew,
                                                  u64* __restrict__ packed,
                                                  ushort* __restrict__ tkt, int nE) {
    int e = blockIdx.x * 256 + threadIdx.x;
    if (e >= nE) return;
    int c = col[e];
    u64 add = (1ull << 32) | (u64)(uint)__float2uint_rn(ew[e] * 4194304.0f);
    u64 old = atomicAdd(&packed[c], add);
    tkt[e] = (ushort)(old >> 32);
}

// ---------------- scan1: dis = rsqrt(1 + wsum) fused; exclusive scan of counts ----------------
__global__ __launch_bounds__(256) void k_scan1(const u64* __restrict__ packed,
                                               float* __restrict__ dis,
                                               int* __restrict__ offs,
                                               int* __restrict__ bsum, int n) {
    __shared__ int s[256];
    int t = threadIdx.x;
    int i = blockIdx.x * 256 + t;
    int v = 0;
    if (i < n) {
        u64 p = packed[i];
        v = (int)(p >> 32);
        float deg = 1.0f + (float)(p & 0xFFFFFFFFull) * 2.384185791015625e-7f;
        dis[i] = rsqrtf(deg);
    }
    s[t] = v;
    __syncthreads();
    for (int d = 1; d < 256; d <<= 1) {
        int a = (t >= d) ? s[t - d] : 0;
        __syncthreads();
        s[t] += a;
        __syncthreads();
    }
    if (i < n) offs[i] = s[t] - v;
    if (t == 255) bsum[blockIdx.x] = s[255];
}

__global__ __launch_bounds__(512) void k_scan2(int* __restrict__ bsum, int nb) {
    __shared__ int s[512];
    int t = threadIdx.x;
    int v = (t < nb) ? bsum[t] : 0;
    s[t] = v;
    __syncthreads();
    for (int d = 1; d < 512; d <<= 1) {
        int a = (t >= d) ? s[t - d] : 0;
        __syncthreads();
        s[t] += a;
        __syncthreads();
    }
    if (t < nb) bsum[t] = s[t] - v;
}

__global__ __launch_bounds__(256) void k_scan3(int* __restrict__ offs,
                                               const int* __restrict__ bsum,
                                               int n, int nE) {
    int i = blockIdx.x * 256 + threadIdx.x;
    if (i < n) offs[i] += bsum[i >> 8];
    if (i == 0) offs[n] = nE;
}

// ---------------- xb' = bf16(dis[r] * x[r]) ----------------
__global__ __launch_bounds__(256) void k_cvt(const float4* __restrict__ x4,
                                             const float* __restrict__ dis,
                                             ushort4* __restrict__ xb4, long total4) {
    long i = (long)blockIdx.x * 256 + threadIdx.x;
    if (i >= total4) return;
    float d = dis[i >> 5];
    float4 v = x4[i];
    ushort4 r;
#define RNE(OUT, F)                                                     \
    {                                                                   \
        uint u = __float_as_uint((F) * d);                              \
        OUT = (ushort)((u + 0x7FFFu + ((u >> 16) & 1u)) >> 16);         \
    }
    RNE(r.x, v.x) RNE(r.y, v.y) RNE(r.z, v.z) RNE(r.w, v.w)
#undef RNE
    xb4[i] = r;
}

// ---------------- WbT[o][k] = bf16(W[k][o]) ----------------
__global__ __launch_bounds__(256) void k_wcvt(const float* __restrict__ W,
                                              ushort* __restrict__ WbT) {
    int idx = blockIdx.x * 256 + threadIdx.x;   // 16384 total
    int k = idx >> 7, o = idx & 127;
    uint u = __float_as_uint(W[idx]);
    WbT[o * 128 + k] = (ushort)((u + 0x7FFFu + ((u >> 16) & 1u)) >> 16);
}

// ---------------- bin edges into CSR (no atomics, no gathers) ----------------
__global__ __launch_bounds__(256) void k_build(const int* __restrict__ ei,
                                               const float* __restrict__ ew,
                                               const int* __restrict__ offs,
                                               const ushort* __restrict__ tkt,
                                               int2* __restrict__ ev, int nE) {
    int e = blockIdx.x * 256 + threadIdx.x;
    if (e >= nE) return;
    int row = ei[e];
    int c = ei[nE + e];
    int pos = offs[c] + tkt[e];
    ev[pos] = make_int2(row, __float_as_int(ew[e]));
}

// ---------------- segment aggregation ----------------
// out[col] = dis[col] * ( xb'[col] + sum_e w_e * xb'[row_e] )   (self-loop = weight-1 edge)
__device__ __forceinline__ float blo(uint u) { return __uint_as_float(u << 16); }
__device__ __forceinline__ float bhi(uint u) { return __uint_as_float(u & 0xFFFF0000u); }

__global__ __launch_bounds__(256) void k_segagg(const ushort* __restrict__ xb,
                                                const int2* __restrict__ ev,
                                                const int* __restrict__ offs,
                                                const float* __restrict__ dis,
                                                float* __restrict__ out, int n) {
    const int lane = threadIdx.x & 15;   // 0..15
    const int sub  = threadIdx.x >> 4;   // 0..15
    const int col  = blockIdx.x * 16 + sub;
    if (col >= n) return;

    uint4 sv = *(const uint4*)(xb + (size_t)col * C + lane * 8);
    float acc[8] = {blo(sv.x), bhi(sv.x), blo(sv.y), bhi(sv.y),
                    blo(sv.z), bhi(sv.z), blo(sv.w), bhi(sv.w)};

    int i = offs[col];
    const int end = offs[col + 1];

#define EDGE(E, V)                                                        \
    {                                                                     \
        float nw = __int_as_float(E.y);                                   \
        acc[0] = fmaf(nw, blo(V.x), acc[0]);                              \
        acc[1] = fmaf(nw, bhi(V.x), acc[1]);                              \
        acc[2] = fmaf(nw, blo(V.y), acc[2]);                              \
        acc[3] = fmaf(nw, bhi(V.y), acc[3]);                              \
        acc[4] = fmaf(nw, blo(V.z), acc[4]);                              \
        acc[5] = fmaf(nw, bhi(V.z), acc[5]);                              \
        acc[6] = fmaf(nw, blo(V.w), acc[6]);                              \
        acc[7] = fmaf(nw, bhi(V.w), acc[7]);                              \
    }

    for (; i + 2 <= end; i += 2) {
        int2 e0 = ev[i], e1 = ev[i + 1];
        uint4 v0 = *(const uint4*)(xb + (size_t)e0.x * C + lane * 8);
        uint4 v1 = *(const uint4*)(xb + (size_t)e1.x * C + lane * 8);
        EDGE(e0, v0)
        EDGE(e1, v1)
    }
    if (i < end) {
        int2 e0 = ev[i];
        uint4 v0 = *(const uint4*)(xb + (size_t)e0.x * C + lane * 8);
        EDGE(e0, v0)
    }
#undef EDGE

    float d = dis[col];
    float4* orow = (float4*)(out + (size_t)col * C) + lane * 2;
    orow[0] = make_float4(d * acc[0], d * acc[1], d * acc[2], d * acc[3]);
    orow[1] = make_float4(d * acc[4], d * acc[5], d * acc[6], d * acc[7]);
}

// ---------------- MFMA GEMM: io = io @ W (in place), swapped operands ----------------
// A = W^T tile (from WbT, 16B contiguous per lane), B = agg^T tile (f32->bf16 in reg).
// D comes out transposed: lane owns 4 consecutive channels of ONE row -> float4 stores.
// No LDS, no barriers, no atomics.
__global__ __launch_bounds__(256, 4) void k_gemm(float* __restrict__ io,
                                                 const ushort* __restrict__ WbT,
                                                 int n) {
    const int t = threadIdx.x;
    const int lane = t & 63;
    const int wv = t >> 6;          // wave 0..3
    const int lr = lane & 15;       // row within 16-row tile (D col)
    const int lk = lane >> 4;       // k-chunk 0..3 (and D row-group = channel group)
    const long m = (long)blockIdx.x * 64 + wv * 16 + lr;
    const bool inr = m < (long)n;

    // ---- B fragments: agg row m, 8 consecutive f32 -> bf16x8 (round-half-up) ----
    bf16x8 b[4];
#pragma unroll
    for (int s = 0; s < 4; ++s) {
        uint4 q0 = make_uint4(0, 0, 0, 0), q1 = q0;
        if (inr) {
            const uint4* p = (const uint4*)(io + (size_t)m * C + s * 32 + lk * 8);
            q0 = p[0];
            q1 = p[1];
        }
        union { uint u[4]; bf16x8 v; } cv;
        cv.u[0] = __builtin_amdgcn_perm(q0.y + 0x8000u, q0.x + 0x8000u, 0x07060302u);
        cv.u[1] = __builtin_amdgcn_perm(q0.w + 0x8000u, q0.z + 0x8000u, 0x07060302u);
        cv.u[2] = __builtin_amdgcn_perm(q1.y + 0x8000u, q1.x + 0x8000u, 0x07060302u);
        cv.u[3] = __builtin_amdgcn_perm(q1.w + 0x8000u, q1.z + 0x8000u, 0x07060302u);
        b[s] = cv.v;
    }

    // ---- MFMA over 8 channel-tiles (ot): acc[ot] = W^T(ot) x agg^T ----
    f32x4 acc[8];
#pragma unroll
    for (int ot = 0; ot < 8; ++ot) acc[ot] = (f32x4){0.f, 0.f, 0.f, 0.f};

#pragma unroll 2
    for (int ot = 0; ot < 8; ++ot) {
        const ushort* wp = WbT + (ot * 16 + lr) * 128 + lk * 8;
        bf16x8 a0 = *(const bf16x8*)(wp);
        bf16x8 a1 = *(const bf16x8*)(wp + 32);
        bf16x8 a2 = *(const bf16x8*)(wp + 64);
        bf16x8 a3 = *(const bf16x8*)(wp + 96);
        acc[ot] = __builtin_amdgcn_mfma_f32_16x16x32_bf16(a0, b[0], acc[ot], 0, 0, 0);
        acc[ot] = __builtin_amdgcn_mfma_f32_16x16x32_bf16(a1, b[1], acc[ot], 0, 0, 0);
        acc[ot] = __builtin_amdgcn_mfma_f32_16x16x32_bf16(a2, b[2], acc[ot], 0, 0, 0);
        acc[ot] = __builtin_amdgcn_mfma_f32_16x16x32_bf16(a3, b[3], acc[ot], 0, 0, 0);
    }

    // ---- store: lane's 4 consecutive channels of its row, per ot ----
    if (inr) {
        float* orow = io + (size_t)m * C + lk * 4;
#pragma unroll
        for (int ot = 0; ot < 8; ++ot)
            *(float4*)(orow + ot * 16) =
                make_float4(acc[ot][0], acc[ot][1], acc[ot][2], acc[ot][3]);
    }
}

// ---------------- BN stats: per-block partials (no global atomics) ----------------
__global__ __launch_bounds__(1024) void k_stats(const float4* __restrict__ o4,
                                                float* __restrict__ part, int n) {
    const int t = threadIdx.x;
    const int cg = t & 31;   // float4 column group
    const int rl = t >> 5;   // 0..31 row lanes
    float4 s = make_float4(0.f, 0.f, 0.f, 0.f);
    float4 q = s;
    for (int r = blockIdx.x * 32 + rl; r < n; r += gridDim.x * 32) {
        float4 v = o4[(size_t)r * 32 + cg];
        s.x += v.x; s.y += v.y; s.z += v.z; s.w += v.w;
        q.x = fmaf(v.x, v.x, q.x); q.y = fmaf(v.y, v.y, q.y);
        q.z = fmaf(v.z, v.z, q.z); q.w = fmaf(v.w, v.w, q.w);
    }
    __shared__ float4 ls[1024];
    __shared__ float4 lq[1024];
    ls[t] = s; lq[t] = q;
    __syncthreads();
    for (int d = 512; d >= 32; d >>= 1) {
        if (t < d) {
            float4 a = ls[t + d], bq = lq[t + d];
            ls[t].x += a.x; ls[t].y += a.y; ls[t].z += a.z; ls[t].w += a.w;
            lq[t].x += bq.x; lq[t].y += bq.y; lq[t].z += bq.z; lq[t].w += bq.w;
        }
        __syncthreads();
    }
    if (t < 32) {
        ((float4*)part)[blockIdx.x * 64 + t] = ls[t];        // s: channels t*4..t*4+3
        ((float4*)part)[blockIdx.x * 64 + 32 + t] = lq[t];   // q
    }
}

__global__ __launch_bounds__(256) void k_finish(const float* __restrict__ part,
                                                float* __restrict__ sums, int nblk) {
    int t = threadIdx.x;   // 0..127 -> sum channel t; 128..255 -> sumsq channel t-128
    float s = 0.f;
    for (int b = blockIdx.x; b < nblk; b += gridDim.x) s += part[b * 256 + t];
    atomicAdd(&sums[t], s);
}

// ---------------- BN apply + ReLU (in place) ----------------
__global__ __launch_bounds__(256) void k_apply(float* __restrict__ out,
                                               const float* __restrict__ sums,
                                               const float* __restrict__ gamma,
                                               const float* __restrict__ beta,
                                               int n) {
    size_t idx = (size_t)blockIdx.x * 256 + threadIdx.x;
    size_t total = (size_t)n * 32;
    if (idx >= total) return;
    int cg = (int)(idx & 31);
    int c0 = cg * 4;
    float inv_n = 1.0f / (float)n;
    float4 v = ((const float4*)out)[idx];
    float4 r;
#define BN1(OUT, VIN, J)                                                   \
    {                                                                      \
        float mean = sums[c0 + J] * inv_n;                                 \
        float var  = fmaxf(sums[C + c0 + J] * inv_n - mean * mean, 0.f);   \
        float sc   = rsqrtf(var + 1e-5f) * gamma[c0 + J];                  \
        OUT = fmaxf(fmaf(VIN - mean, sc, beta[c0 + J]), 0.f);              \
    }
    BN1(r.x, v.x, 0)
    BN1(r.y, v.y, 1)
    BN1(r.z, v.z, 2)
    BN1(r.w, v.w, 3)
#undef BN1
    ((float4*)out)[idx] = r;
}

extern "C" void kernel_launch(void* const* d_in, const int* in_sizes, int n_in,
                              void* d_out, int out_size, void* d_ws, size_t ws_size,
                              hipStream_t stream) {
    const float* x     = (const float*)d_in[0];
    const int*   ei    = (const int*)d_in[1];   // [2, E]: row = ei[e], col = ei[E+e]
    const float* ew    = (const float*)d_in[2];
    const float* W     = (const float*)d_in[3];
    const float* gamma = (const float*)d_in[4];
    const float* beta  = (const float*)d_in[5];

    const int n  = in_sizes[0] / C;
    const int nE = in_sizes[2];
    const int nb = (n + 255) / 256;
    const int SB = 256;  // k_stats blocks

    float* out = (float*)d_out;
    char* ws = (char*)d_ws;

    int2*   ev     = (int2*)ws;                               // E*8 B
    ushort* xb     = (ushort*)(ws + (size_t)nE * 8);          // n*C*2 B
    char*   p      = ws + (size_t)nE * 8 + (size_t)n * C * 2;
    u64*    packed = (u64*)p;              p += (size_t)n * 8;
    ushort* WbT    = (ushort*)p;           p += 128 * 128 * 2;
    float*  dis    = (float*)p;            p += (size_t)n * 4;
    int*    offs   = (int*)p;              p += (size_t)(n + 1) * 4;
    ushort* tkt    = (ushort*)p;           p += (size_t)nE * 2;
    int*    bsum   = (int*)p;              p += 512 * 4;
    float*  sums   = (float*)p;            p += 256 * 4;
    float*  part   = (float*)p;            p += (size_t)SB * 256 * 4;

    const long total4 = (long)n * 32;  // n*C/4

    hipMemsetAsync(packed, 0, (size_t)n * 8, stream);
    hipMemsetAsync(sums, 0, 256 * 4, stream);

    k_deg_hist<<<(nE + 255) / 256, 256, 0, stream>>>(ei + nE, ew, packed, tkt, nE);
    k_wcvt<<<64, 256, 0, stream>>>(W, WbT);
    k_scan1<<<nb, 256, 0, stream>>>(packed, dis, offs, bsum, n);
    k_scan2<<<1, 512, 0, stream>>>(bsum, nb);
    k_scan3<<<nb, 256, 0, stream>>>(offs, bsum, n, nE);
    k_cvt<<<(int)((total4 + 255) / 256), 256, 0, stream>>>((const float4*)x, dis, (ushort4*)xb, total4);
    k_build<<<(nE + 255) / 256, 256, 0, stream>>>(ei, ew, offs, tkt, ev, nE);
    k_segagg<<<(n + 15) / 16, 256, 0, stream>>>(xb, ev, offs, dis, out, n);
    k_gemm<<<(n + 63) / 64, 256, 0, stream>>>(out, WbT, n);
    k_stats<<<SB, 1024, 0, stream>>>((const float4*)out, part, n);
    k_finish<<<16, 256, 0, stream>>>(part, sums, SB);
    k_apply<<<(int)((total4 + 255) / 256), 256, 0, stream>>>(out, sums, gamma, beta, n);
}